// Round 3
// baseline (691.863 us; speedup 1.0000x reference)
//
#include <hip/hip_runtime.h>
#include <cmath>

#define B_    16
#define HH    56
#define WWI   56
#define C_    256
#define NH_   8
#define WS_   7
#define SS_   3
#define HD_   32
#define NTOK  50176          // B*56*56
#define NN    49             // window size squared
#define SCALE_ 0.17677669529663689f
#define EPS_  1e-5f

typedef __bf16  bf16x8  __attribute__((ext_vector_type(8)));
typedef float   f32x4   __attribute__((ext_vector_type(4)));
typedef unsigned short ushort8v __attribute__((ext_vector_type(8)));

__device__ __forceinline__ unsigned short f2bf(float f) {
    unsigned int u = __float_as_uint(f);
    unsigned int r = u + 0x7FFFu + ((u >> 16) & 1u);   // RNE
    return (unsigned short)(r >> 16);
}
__device__ __forceinline__ float bf2f(unsigned short h) {
    return __uint_as_float(((unsigned int)h) << 16);
}
// tanh-form GELU: |err| <= ~3e-3 vs exact erf form; hw v_exp_f32 + rcp
__device__ __forceinline__ float gelu_t(float x) {
    float t = 0.7978845608028654f * (x + 0.044715f * x * x * x);
    float e = __expf(2.0f * t);
    float th = 1.0f - 2.0f * __builtin_amdgcn_rcpf(e + 1.0f);
    return 0.5f * x * (1.0f + th);
}

// ---------------- weight fp32 -> bf16 conversion ----------------
__global__ __launch_bounds__(256) void convw_k(
    const float* __restrict__ qkvw, const float* __restrict__ projw,
    const float* __restrict__ fc1w, const float* __restrict__ fc2w,
    unsigned short* __restrict__ dst)
{
    int i = blockIdx.x * 256 + threadIdx.x;          // < 786432
    float v;
    if      (i < 196608) v = qkvw[i];
    else if (i < 262144) v = projw[i - 196608];
    else if (i < 524288) v = fc1w[i - 262144];
    else                 v = fc2w[i - 524288];
    dst[i] = f2bf(v);
}

// ---------------- combined rel-bias + shift-mask table, bf16 ----------------
__global__ __launch_bounds__(256) void cb_k(
    const float* __restrict__ mask, const float* __restrict__ relb,
    unsigned short* __restrict__ cb)
{
    int s = blockIdx.x;                 // 512 slices = 64 windows * 8 heads
    int wi = s >> 3, head = s & 7;
    for (int p = threadIdx.x; p < 2408; p += 256) {
        float v = 0.0f;
        if (p < 2401) {
            int i = p / NN, j = p - i * NN;
            int di = i / 7 - j / 7 + 6, dj = i % 7 - j % 7 + 6;
            v = relb[(di * 13 + dj) * NH_ + head] + mask[(size_t)wi * 2401 + p];
        }
        cb[(size_t)s * 2408 + p] = f2bf(v);
    }
}

// ---------------- LayerNorm (+optional shift+window-partition) ----------------
__global__ __launch_bounds__(256) void ln_k(
    const float* __restrict__ x, const float* __restrict__ g,
    const float* __restrict__ bta, unsigned short* __restrict__ dst, int shifted)
{
    int wave = threadIdx.x >> 6, lane = threadIdx.x & 63;
    int tok = blockIdx.x * 4 + wave;                  // < 50176
    const float4 v = *(const float4*)(x + (size_t)tok * C_ + lane * 4);
    float s = v.x + v.y + v.z + v.w;
    float q = v.x*v.x + v.y*v.y + v.z*v.z + v.w*v.w;
    for (int o = 32; o > 0; o >>= 1) { s += __shfl_xor(s, o, 64); q += __shfl_xor(q, o, 64); }
    float mu  = s * (1.0f / C_);
    float var = q * (1.0f / C_) - mu * mu;
    float rs  = rsqrtf(var + EPS_);
    float4 gg = *(const float4*)(g   + lane * 4);
    float4 bb = *(const float4*)(bta + lane * 4);
    float y0 = (v.x - mu) * rs * gg.x + bb.x;
    float y1 = (v.y - mu) * rs * gg.y + bb.y;
    float y2 = (v.z - mu) * rs * gg.z + bb.z;
    float y3 = (v.w - mu) * rs * gg.w + bb.w;
    size_t di;
    if (shifted) {
        int b = tok / 3136, p = tok % 3136;
        int ph = p / 56, pw = p % 56;
        int sh = ph - SS_; if (sh < 0) sh += HH;
        int sw = pw - SS_; if (sw < 0) sw += WWI;
        int bw = b * 64 + (sh / WS_) * 8 + (sw / WS_);
        int n  = (sh % WS_) * WS_ + (sw % WS_);
        di = ((size_t)bw * NN + n) * C_ + lane * 4;
    } else {
        di = (size_t)tok * C_ + lane * 4;
    }
    unsigned int lo = (unsigned int)f2bf(y0) | ((unsigned int)f2bf(y1) << 16);
    unsigned int hi = (unsigned int)f2bf(y2) | ((unsigned int)f2bf(y3) << 16);
    uint2 u; u.x = lo; u.y = hi;
    *(uint2*)(dst + di) = u;
}

// ---------------- MFMA GEMM, 128x128 tile, BK=32, REGISTER staging ----------
// Round-2 evidence: FC1 and FC2 both stage 401 MB via global_load_lds and both
// take ~62 us (6.4 TB/s = ~10.4 B/cyc/CU) with every pipe <30% busy and FC1
// nearly all L2-hit -> the DMA path itself saturates ~10-11 B/cyc/CU.
// Fix: stage via buffer_load->VGPR->ds_write (HK-style reg staging, ~24 B/cyc
// demonstrated), depth-2 in regs + 2 LDS buffers, ONE barrier per K-step.
// Per K-step k: issue loads of tile k+2 -> regset[k&1]; ds_read frags of tile
// k from buf[k&1] + 16 MFMA; ds_write regset[(k+1)&1] -> buf[(k+1)&1]
// (compiler emits the precise vmcnt wait); lgkmcnt(0); s_barrier.
// LDS layout/swizzle byte-identical to round 2 (slot q of row r holds global
// k-chunk q ^ ((r>>1)&3); reads undo it with sw8) -> bank-conflict-free.
template<int EPI, int NT>
__global__ __launch_bounds__(256) void gemm_k(
    const unsigned short* __restrict__ A, const unsigned short* __restrict__ Bt,
    int K, const float* __restrict__ bias,
    const float* __restrict__ resid, float* __restrict__ outF,
    unsigned short* __restrict__ outQ, unsigned short* __restrict__ outK,
    unsigned short* __restrict__ outV)
{
    // smem: 2 x 16KB staging buffers; epilogue bounce overlays [0, 34816)
    __shared__ __align__(16) unsigned char smem[34816];
    const int tid = threadIdx.x;
    const int lin = blockIdx.x;
    const int xcd = lin & 7, t = lin >> 3;
    const int m0 = (xcd * 49 + t / NT) * 128;
    const int n0 = (t % NT) * 128;
    const int wave = tid >> 6, lane = tid & 63, quad = lane >> 4, l16 = lane & 15;
    const int wm = wave >> 1, wn = wave & 1;
    // staging row/col: row = tid>>2; source chunk = (tid&3) ^ ((row>>1)&3)
    const int r0 = tid >> 2;
    const int c0 = (((tid & 3) ^ ((tid >> 3) & 3)) * 8);

    const unsigned short* pA0 = A  + (size_t)(m0 + r0) * K + c0;
    const unsigned short* pA1 = A  + (size_t)(m0 + r0 + 64) * K + c0;
    const unsigned short* pB0 = Bt + (size_t)(n0 + r0) * K + c0;
    const unsigned short* pB1 = Bt + (size_t)(n0 + r0 + 64) * K + c0;
    // per-buffer layout (16KB): A0 [0,4K) A1 [4K,8K) B0 [8K,12K) B1 [12K,16K)
    unsigned char* stg = smem + tid * 16;
    // read-side swizzle slot (loop-invariant)
    const int sw8 = (quad ^ ((l16 >> 1) & 3)) * 8;

    f32x4 acc[4][4] = {};
    const int nk = K >> 5;

    uint4 rA0[2], rA1[2], rB0[2], rB1[2];
    // prologue: load tiles 0,1 (8 loads in flight), publish tile 0 -> buf0
    rA0[0] = *(const uint4*)(pA0);      rA1[0] = *(const uint4*)(pA1);
    rB0[0] = *(const uint4*)(pB0);      rB1[0] = *(const uint4*)(pB1);
    rA0[1] = *(const uint4*)(pA0 + 32); rA1[1] = *(const uint4*)(pA1 + 32);
    rB0[1] = *(const uint4*)(pB0 + 32); rB1[1] = *(const uint4*)(pB1 + 32);
    *(uint4*)(stg        ) = rA0[0];
    *(uint4*)(stg +  4096) = rA1[0];
    *(uint4*)(stg +  8192) = rB0[0];
    *(uint4*)(stg + 12288) = rB1[0];
    __asm volatile("s_waitcnt lgkmcnt(0)\n\ts_barrier" ::: "memory");

    #define COMPUTE(p_) { \
        const unsigned short* sA = (const unsigned short*)(smem + (p_) * 16384); \
        const unsigned short* sB = sA + 4096; \
        bf16x8 af[4], bfr[4]; \
        _Pragma("unroll") \
        for (int tt = 0; tt < 4; ++tt) { \
            af[tt]  = __builtin_bit_cast(bf16x8, *(const ushort8v*)(sA + (wm * 64 + tt * 16 + l16) * 32 + sw8)); \
            bfr[tt] = __builtin_bit_cast(bf16x8, *(const ushort8v*)(sB + (wn * 64 + tt * 16 + l16) * 32 + sw8)); \
        } \
        _Pragma("unroll") \
        for (int mt = 0; mt < 4; ++mt) \
            _Pragma("unroll") \
            for (int nt = 0; nt < 4; ++nt) \
                acc[mt][nt] = __builtin_amdgcn_mfma_f32_16x16x32_bf16(af[mt], bfr[nt], acc[mt][nt], 0, 0, 0); }

    for (int kk = 0; kk < nk; kk += 2) {
        // ---- even step: consume tile kk from buf0; set0 regs are free ----
        if (kk + 2 < nk) {
            const int k2 = (kk + 2) << 5;
            rA0[0] = *(const uint4*)(pA0 + k2); rA1[0] = *(const uint4*)(pA1 + k2);
            rB0[0] = *(const uint4*)(pB0 + k2); rB1[0] = *(const uint4*)(pB1 + k2);
        }
        COMPUTE(0);
        // publish tile kk+1 (set1) -> buf1 (WAR-safe: barrier'd last step)
        *(uint4*)(stg + 16384        ) = rA0[1];
        *(uint4*)(stg + 16384 +  4096) = rA1[1];
        *(uint4*)(stg + 16384 +  8192) = rB0[1];
        *(uint4*)(stg + 16384 + 12288) = rB1[1];
        __asm volatile("s_waitcnt lgkmcnt(0)\n\ts_barrier" ::: "memory");

        // ---- odd step: consume tile kk+1 from buf1; set1 regs are free ----
        if (kk + 3 < nk) {
            const int k3 = (kk + 3) << 5;
            rA0[1] = *(const uint4*)(pA0 + k3); rA1[1] = *(const uint4*)(pA1 + k3);
            rB0[1] = *(const uint4*)(pB0 + k3); rB1[1] = *(const uint4*)(pB1 + k3);
        }
        COMPUTE(1);
        if (kk + 2 < nk) {   // publish tile kk+2 (set0) -> buf0
            *(uint4*)(stg        ) = rA0[0];
            *(uint4*)(stg +  4096) = rA1[0];
            *(uint4*)(stg +  8192) = rB0[0];
            *(uint4*)(stg + 12288) = rB1[0];
        }
        __asm volatile("s_waitcnt lgkmcnt(0)\n\ts_barrier" ::: "memory");
    }
    #undef COMPUTE

    float b4[4];
    #pragma unroll
    for (int nt = 0; nt < 4; ++nt) b4[nt] = bias[n0 + wn * 64 + nt * 16 + l16];

    if (EPI == 0 || EPI == 2) {
        // ---- bf16 output: bounce to LDS, store packed uint4 ----
        unsigned short (*swB)[136] = (unsigned short (*)[136])smem;  // 128x136x2 = 34816B
        const int seg = n0 >> 8;                      // EPI0: 0=q 1=k 2=v (block never straddles)
        const float qs = (EPI == 0 && seg == 0) ? SCALE_ : 1.0f;
        #pragma unroll
        for (int mt = 0; mt < 4; ++mt)
            #pragma unroll
            for (int nt = 0; nt < 4; ++nt)
                #pragma unroll
                for (int r = 0; r < 4; ++r) {
                    float v = acc[mt][nt][r] + b4[nt];
                    if (EPI == 0) v *= qs; else v = gelu_t(v);
                    swB[wm * 64 + mt * 16 + quad * 4 + r][wn * 64 + nt * 16 + l16] = f2bf(v);
                }
        __syncthreads();
        if (EPI == 0) {
            unsigned short* dstp = seg == 0 ? outQ : (seg == 1 ? outK : outV);
            const int nbase = n0 & 255;
            for (int tt = tid; tt < 2048; tt += 256) {
                int row = tt >> 4, c8 = (tt & 15) * 8;
                int m = m0 + row, bw = m / NN, nw = m - bw * NN;
                int cc = nbase + c8;
                uint4 u = *(uint4*)&swB[row][c8];
                *(uint4*)&dstp[(((size_t)bw * NH_ + (cc >> 5)) * NN + nw) * HD_ + (cc & 31)] = u;
            }
        } else {
            for (int tt = tid; tt < 2048; tt += 256) {
                int row = tt >> 4, c8 = (tt & 15) * 8;
                uint4 u = *(uint4*)&swB[row][c8];
                *(uint4*)&outQ[(size_t)(m0 + row) * 1024 + n0 + c8] = u;
            }
        }
    } else {
        // ---- fp32 output: two 64-row passes through LDS, float4 stores ----
        float (*swF)[132] = (float (*)[132])smem;     // 64x132x4 = 33792B
        #pragma unroll
        for (int p = 0; p < 2; ++p) {
            __syncthreads();
            if (wm == p) {
                #pragma unroll
                for (int mt = 0; mt < 4; ++mt)
                    #pragma unroll
                    for (int nt = 0; nt < 4; ++nt)
                        #pragma unroll
                        for (int r = 0; r < 4; ++r)
                            swF[mt * 16 + quad * 4 + r][wn * 64 + nt * 16 + l16] = acc[mt][nt][r] + b4[nt];
            }
            __syncthreads();
            for (int tt = tid; tt < 2048; tt += 256) {
                int rl = tt >> 5, c4 = (tt & 31) * 4;
                size_t adr;
                if (EPI == 1) {                       // window-reverse + unshift
                    int m = m0 + p * 64 + rl, bw = m / NN, nw = m - bw * NN;
                    int b = bw >> 6, wi = bw & 63;
                    int sh = (wi >> 3) * WS_ + nw / WS_;
                    int sw = (wi & 7) * WS_ + nw % WS_;
                    int ph = sh + SS_; if (ph >= HH)  ph -= HH;
                    int pw = sw + SS_; if (pw >= WWI) pw -= WWI;
                    adr = ((size_t)b * 3136 + ph * 56 + pw) * C_ + n0 + c4;
                } else {
                    adr = (size_t)(m0 + p * 64 + rl) * C_ + n0 + c4;
                }
                float4 u = *(float4*)&swF[rl][c4];
                const float4 rr = (EPI == 1) ? *(const float4*)&resid[adr]
                                             : *(const float4*)&outF[adr];
                u.x += rr.x; u.y += rr.y; u.z += rr.z; u.w += rr.w;
                *(float4*)&outF[adr] = u;
            }
        }
    }
}

// ---------------- MFMA attention: one block per (window, head) ----------------
__global__ __launch_bounds__(256) void attn_k(
    const unsigned short* __restrict__ qb, const unsigned short* __restrict__ kb,
    const unsigned short* __restrict__ vb, const unsigned short* __restrict__ cb,
    unsigned short* __restrict__ ob)
{
    __shared__ unsigned short qs[64][40];   // Q rows (pad 40: frag reads 2-way free)
    __shared__ unsigned short ks[64][40];   // K rows
    __shared__ unsigned short vt[32][72];   // V^T: [d][j], j padded to 64 (zeroed 49..63)
    __shared__ unsigned short sp[64][72];   // P bf16, A-layout rows
    __shared__ unsigned short cbs[2408];    // bias+mask slice
    const int tid = threadIdx.x;
    const int bw = blockIdx.x >> 3, head = blockIdx.x & 7;
    const size_t base = (size_t)blockIdx.x * (NN * HD_);   // (bw*8+head)*1568

    for (int t = tid; t < 588; t += 256) {
        int seg = t / 196, idx = t - seg * 196;
        int e = idx * 8;                          // 8 shorts = 16B
        const unsigned short* src = (seg == 0 ? qb : seg == 1 ? kb : vb) + base + e;
        uint4 u = *(const uint4*)src;
        if (seg == 0)      *(uint4*)&qs[e >> 5][e & 31] = u;
        else if (seg == 1) *(uint4*)&ks[e >> 5][e & 31] = u;
        else {
            int n = e >> 5, hd = e & 31;
            const unsigned short* pu = (const unsigned short*)&u;
            #pragma unroll
            for (int uu = 0; uu < 8; ++uu) vt[hd + uu][n] = pu[uu];
        }
    }
    {
        const unsigned short* cbase = cb + (size_t)(((bw & 63) * 8 + head)) * 2408;
        for (int t = tid; t < 301; t += 256)
            *(uint4*)&cbs[t * 8] = *(const uint4*)(cbase + t * 8);
        for (int t = tid; t < 480; t += 256) vt[t / 15][NN + t % 15] = 0;  // zero j=49..63
    }
    __syncthreads();

    const int wave = tid >> 6, lane = tid & 63, quad = lane >> 4, l16 = lane & 15;
    const f32x4 zz = {};

    bf16x8 afq = __builtin_bit_cast(bf16x8, *(const ushort8v*)&qs[wave * 16 + l16][quad * 8]);
    f32x4 s4[4];
    #pragma unroll
    for (int jt = 0; jt < 4; ++jt) {
        bf16x8 bk = __builtin_bit_cast(bf16x8, *(const ushort8v*)&ks[jt * 16 + l16][quad * 8]);
        s4[jt] = __builtin_amdgcn_mfma_f32_16x16x32_bf16(afq, bk, zz, 0, 0, 0);
    }

    #pragma unroll
    for (int r = 0; r < 4; ++r) {
        int i = wave * 16 + quad * 4 + r;
        float vals[4];
        #pragma unroll
        for (int jt = 0; jt < 4; ++jt) {
            int j = jt * 16 + l16;
            vals[jt] = (i < NN && j < NN) ? s4[jt][r] + bf2f(cbs[i * NN + j]) : -1e30f;
        }
        float mx = fmaxf(fmaxf(vals[0], vals[1]), fmaxf(vals[2], vals[3]));
        #pragma unroll
        for (int o = 1; o < 16; o <<= 1) mx = fmaxf(mx, __shfl_xor(mx, o, 64));
        float e[4], sum = 0.0f;
        #pragma unroll
        for (int jt = 0; jt < 4; ++jt) { e[jt] = __expf(vals[jt] - mx); sum += e[jt]; }
        #pragma unroll
        for (int o = 1; o < 16; o <<= 1) sum += __shfl_xor(sum, o, 64);
        float inv = 1.0f / sum;
        #pragma unroll
        for (int jt = 0; jt < 4; ++jt) sp[i][jt * 16 + l16] = f2bf(e[jt] * inv);
    }
    __syncthreads();

    bf16x8 ap[2];
    #pragma unroll
    for (int kt = 0; kt < 2; ++kt)
        ap[kt] = __builtin_bit_cast(bf16x8, *(const ushort8v*)&sp[wave * 16 + l16][kt * 32 + quad * 8]);
    f32x4 o4[2] = {};
    #pragma unroll
    for (int nt = 0; nt < 2; ++nt)
        #pragma unroll
        for (int kt = 0; kt < 2; ++kt) {
            bf16x8 bv = __builtin_bit_cast(bf16x8, *(const ushort8v*)&vt[nt * 16 + l16][kt * 32 + quad * 8]);
            o4[nt] = __builtin_amdgcn_mfma_f32_16x16x32_bf16(ap[kt], bv, o4[nt], 0, 0, 0);
        }
    #pragma unroll
    for (int nt = 0; nt < 2; ++nt)
        #pragma unroll
        for (int r = 0; r < 4; ++r) {
            int i = wave * 16 + quad * 4 + r;
            if (i < NN)
                ob[((size_t)bw * NN + i) * C_ + head * HD_ + nt * 16 + l16] = f2bf(o4[nt][r]);
        }
}

extern "C" void kernel_launch(void* const* d_in, const int* in_sizes, int n_in,
                              void* d_out, int out_size, void* d_ws, size_t ws_size,
                              hipStream_t stream)
{
    const float* x     = (const float*)d_in[0];
    const float* mask  = (const float*)d_in[1];
    const float* n1g   = (const float*)d_in[2];
    const float* n1b   = (const float*)d_in[3];
    const float* qkvw  = (const float*)d_in[4];
    const float* qkvb  = (const float*)d_in[5];
    const float* relb  = (const float*)d_in[6];
    const float* projw = (const float*)d_in[7];
    const float* projb = (const float*)d_in[8];
    const float* n2g   = (const float*)d_in[9];
    const float* n2b   = (const float*)d_in[10];
    const float* fc1w  = (const float*)d_in[11];
    const float* fc1b  = (const float*)d_in[12];
    const float* fc2w  = (const float*)d_in[13];
    const float* fc2b  = (const float*)d_in[14];
    float* out = (float*)d_out;

    unsigned short* wq = (unsigned short*)d_ws;   // all weights bf16, contiguous
    unsigned short* wp = wq + 196608;
    unsigned short* w1 = wq + 262144;
    unsigned short* w2 = wq + 524288;
    unsigned short* hw = wq + 786432;             // LN1-shift-partitioned (50176,256) bf16
    unsigned short* qb = hw + 12845056;           // (1024,8,49,32) bf16
    unsigned short* kb = qb + 12845056;
    unsigned short* vb = kb + 12845056;
    unsigned short* ob = vb + 12845056;           // attn out, windowed (50176,256) bf16
    unsigned short* h2 = ob + 12845056;           // LN2 out (50176,256) bf16
    unsigned short* a1 = h2 + 12845056;           // GELU(fc1) (50176,1024) bf16
    unsigned short* cbt = a1;                     // cb aliases a1 (attn_k finishes before FC1 writes a1)

    convw_k<<<3072, 256, 0, stream>>>(qkvw, projw, fc1w, fc2w, wq);
    cb_k<<<512, 256, 0, stream>>>(mask, relb, cbt);
    ln_k<<<12544, 256, 0, stream>>>(x, n1g, n1b, hw, 1);
    gemm_k<0, 6><<<392 * 6, 256, 0, stream>>>(hw, wq, 256, qkvb, nullptr, nullptr, qb, kb, vb);
    attn_k<<<8192, 256, 0, stream>>>(qb, kb, vb, cbt, ob);
    gemm_k<1, 2><<<392 * 2, 256, 0, stream>>>(ob, wp, 256, projb, x, out, nullptr, nullptr, nullptr);
    ln_k<<<12544, 256, 0, stream>>>(out, n2g, n2b, h2, 0);
    gemm_k<2, 8><<<392 * 8, 256, 0, stream>>>(h2, w1, 256, fc1b, nullptr, nullptr, a1, nullptr, nullptr);
    gemm_k<3, 2><<<392 * 2, 256, 0, stream>>>(a1, w2, 1024, fc2b, nullptr, out, nullptr, nullptr, nullptr);
}

// Round 4
// 401.370 us; speedup vs baseline: 1.7238x; 1.7238x over previous
//
#include <hip/hip_runtime.h>
#include <cmath>

#define B_    16
#define HH    56
#define WWI   56
#define C_    256
#define NH_   8
#define WS_   7
#define SS_   3
#define HD_   32
#define NTOK  50176          // B*56*56
#define NN    49             // window size squared
#define SCALE_ 0.17677669529663689f
#define EPS_  1e-5f

typedef __bf16  bf16x8  __attribute__((ext_vector_type(8)));
typedef float   f32x4   __attribute__((ext_vector_type(4)));
typedef unsigned short ushort8v __attribute__((ext_vector_type(8)));

__device__ __forceinline__ unsigned short f2bf(float f) {
    unsigned int u = __float_as_uint(f);
    unsigned int r = u + 0x7FFFu + ((u >> 16) & 1u);   // RNE
    return (unsigned short)(r >> 16);
}
__device__ __forceinline__ float bf2f(unsigned short h) {
    return __uint_as_float(((unsigned int)h) << 16);
}
// tanh-form GELU: |err| <= ~3e-3 vs exact erf form; hw v_exp_f32 + rcp
__device__ __forceinline__ float gelu_t(float x) {
    float t = 0.7978845608028654f * (x + 0.044715f * x * x * x);
    float e = __expf(2.0f * t);
    float th = 1.0f - 2.0f * __builtin_amdgcn_rcpf(e + 1.0f);
    return 0.5f * x * (1.0f + th);
}

// async global->LDS DMA, 16B per lane; deposits at wave-uniform lds base + lane*16
__device__ __forceinline__ void gload_lds16(const unsigned short* g, unsigned short* l) {
    __builtin_amdgcn_global_load_lds(
        (const __attribute__((address_space(1))) unsigned int*)g,
        (__attribute__((address_space(3))) unsigned int*)l, 16, 0, 0);
}

// ---------------- weight fp32 -> bf16 conversion ----------------
__global__ __launch_bounds__(256) void convw_k(
    const float* __restrict__ qkvw, const float* __restrict__ projw,
    const float* __restrict__ fc1w, const float* __restrict__ fc2w,
    unsigned short* __restrict__ dst)
{
    int i = blockIdx.x * 256 + threadIdx.x;          // < 786432
    float v;
    if      (i < 196608) v = qkvw[i];
    else if (i < 262144) v = projw[i - 196608];
    else if (i < 524288) v = fc1w[i - 262144];
    else                 v = fc2w[i - 524288];
    dst[i] = f2bf(v);
}

// ---------------- combined rel-bias + shift-mask table, bf16 ----------------
__global__ __launch_bounds__(256) void cb_k(
    const float* __restrict__ mask, const float* __restrict__ relb,
    unsigned short* __restrict__ cb)
{
    int s = blockIdx.x;                 // 512 slices = 64 windows * 8 heads
    int wi = s >> 3, head = s & 7;
    for (int p = threadIdx.x; p < 2408; p += 256) {
        float v = 0.0f;
        if (p < 2401) {
            int i = p / NN, j = p - i * NN;
            int di = i / 7 - j / 7 + 6, dj = i % 7 - j % 7 + 6;
            v = relb[(di * 13 + dj) * NH_ + head] + mask[(size_t)wi * 2401 + p];
        }
        cb[(size_t)s * 2408 + p] = f2bf(v);
    }
}

// ---------------- LayerNorm (+optional shift+window-partition) ----------------
__global__ __launch_bounds__(256) void ln_k(
    const float* __restrict__ x, const float* __restrict__ g,
    const float* __restrict__ bta, unsigned short* __restrict__ dst, int shifted)
{
    int wave = threadIdx.x >> 6, lane = threadIdx.x & 63;
    int tok = blockIdx.x * 4 + wave;                  // < 50176
    const float4 v = *(const float4*)(x + (size_t)tok * C_ + lane * 4);
    float s = v.x + v.y + v.z + v.w;
    float q = v.x*v.x + v.y*v.y + v.z*v.z + v.w*v.w;
    for (int o = 32; o > 0; o >>= 1) { s += __shfl_xor(s, o, 64); q += __shfl_xor(q, o, 64); }
    float mu  = s * (1.0f / C_);
    float var = q * (1.0f / C_) - mu * mu;
    float rs  = rsqrtf(var + EPS_);
    float4 gg = *(const float4*)(g   + lane * 4);
    float4 bb = *(const float4*)(bta + lane * 4);
    float y0 = (v.x - mu) * rs * gg.x + bb.x;
    float y1 = (v.y - mu) * rs * gg.y + bb.y;
    float y2 = (v.z - mu) * rs * gg.z + bb.z;
    float y3 = (v.w - mu) * rs * gg.w + bb.w;
    size_t di;
    if (shifted) {
        int b = tok / 3136, p = tok % 3136;
        int ph = p / 56, pw = p % 56;
        int sh = ph - SS_; if (sh < 0) sh += HH;
        int sw = pw - SS_; if (sw < 0) sw += WWI;
        int bw = b * 64 + (sh / WS_) * 8 + (sw / WS_);
        int n  = (sh % WS_) * WS_ + (sw % WS_);
        di = ((size_t)bw * NN + n) * C_ + lane * 4;
    } else {
        di = (size_t)tok * C_ + lane * 4;
    }
    unsigned int lo = (unsigned int)f2bf(y0) | ((unsigned int)f2bf(y1) << 16);
    unsigned int hi = (unsigned int)f2bf(y2) | ((unsigned int)f2bf(y3) << 16);
    uint2 u; u.x = lo; u.y = hi;
    *(uint2*)(dst + di) = u;
}

// ---------------- MFMA GEMM, 256x128 tile, BK=32, depth-3 pipelined DMA ------
// Round-3 lesson: register staging spills (410MB scratch writes) -> DMA staging
// retained. Round-2 evidence: per-block-K-step wall latency dominates (FC1 L2-
// hot and FC2 HBM-heavy both pin at 10.4 B/cyc/CU staged; m97 same mix does
// 23); so halve the block-K-step count by doubling the tile: BM=256, BN=128,
// 4 waves, per-wave 128x64 output (acc[8][4], HK's per-wave shape), 32 MFMA +
// 12 ds_read per wave per K-step. Schedule/swizzle IDENTICAL to round 2,
// rescaled: 6 DMA/wave/tile, depth-3 buffers, vmcnt(12)/(6)/(0).
// LDS 3 x 24KB = 72KB -> 2 blocks/CU.
template<int EPI, int NT>
__global__ __launch_bounds__(256, 2) void gemm_k(
    const unsigned short* __restrict__ A, const unsigned short* __restrict__ Bt,
    int K, const float* __restrict__ bias,
    const float* __restrict__ resid, float* __restrict__ outF,
    unsigned short* __restrict__ outQ, unsigned short* __restrict__ outK,
    unsigned short* __restrict__ outV)
{
    // smem: 3 x 24KB staging; epilogue overlays (max 69632B bf16 bounce)
    __shared__ __align__(16) unsigned char smem[73728];
    const int tid = threadIdx.x;
    const int nwg = 196 * NT;
    const int xcd = blockIdx.x & 7, t = blockIdx.x >> 3;
    const int wg = xcd * (nwg >> 3) + t;          // nwg % 8 == 0 for all calls
    const int m0 = (wg / NT) * 256;
    const int n0 = (wg % NT) * 128;
    const int wave = tid >> 6, lane = tid & 63, quad = lane >> 4, l16 = lane & 15;
    const int wm = wave >> 1, wn = wave & 1;      // wave owns [wm*128, +128) x [wn*64, +64)
    // staging: 24 DMA instrs/K-step; instr id covers 16 rows x 64B; wave w owns
    // ids 6w..6w+5. ids 0..15 = A rows id*16..; ids 16..23 = B rows (id-16)*16.
    // swizzle: slot s of row r holds global chunk s ^ ((r>>1)&3); linear LDS
    // dest (base + lane*16), pre-permuted per-lane global source chunk.
    const int c0 = (((lane & 3) ^ ((lane >> 3) & 3)) * 8);
    const unsigned short* p6[6];
    unsigned dof[6];
    #pragma unroll
    for (int i = 0; i < 6; ++i) {
        int id = wave * 6 + i;
        p6[i] = (id < 16 ? A  + (size_t)(m0 + id * 16 + (lane >> 2)) * K
                         : Bt + (size_t)(n0 + (id - 16) * 16 + (lane >> 2)) * K) + c0;
        dof[i] = id * 1024;                       // A region [0,16K), B [16K,24K)
    }
    // read-side swizzle slot (loop-invariant; frag row base multiple of 16)
    const int sw8 = (quad ^ ((l16 >> 1) & 3)) * 8;

    f32x4 acc[8][4] = {};
    const int nk = K >> 5;

    #define STAGE(kt_, p_) { \
        unsigned char* bb_ = smem + (p_) * 24576; \
        const int ko_ = (kt_) << 5; \
        _Pragma("unroll") \
        for (int i_ = 0; i_ < 6; ++i_) \
            gload_lds16(p6[i_] + ko_, (unsigned short*)(bb_ + dof[i_])); }

    STAGE(0, 0);
    STAGE(1, 1);
    int bufc = 0;
    for (int kk = 0; kk < nk; ++kk) {
        if (kk + 2 < nk) {
            int bufn = bufc + 2; if (bufn >= 3) bufn -= 3;
            STAGE(kk + 2, bufn);
            __asm volatile("s_waitcnt vmcnt(12)\n\ts_barrier" ::: "memory");
        } else if (kk + 1 < nk) {
            __asm volatile("s_waitcnt vmcnt(6)\n\ts_barrier" ::: "memory");
        } else {
            __asm volatile("s_waitcnt vmcnt(0)\n\ts_barrier" ::: "memory");
        }
        const unsigned short* sA = (const unsigned short*)(smem + bufc * 24576);
        const unsigned short* sB = sA + 8192;     // B at byte 16384
        bf16x8 af[8], bfr[4];
        #pragma unroll
        for (int tt = 0; tt < 8; ++tt)
            af[tt]  = __builtin_bit_cast(bf16x8, *(const ushort8v*)(sA + (wm * 128 + tt * 16 + l16) * 32 + sw8));
        #pragma unroll
        for (int tt = 0; tt < 4; ++tt)
            bfr[tt] = __builtin_bit_cast(bf16x8, *(const ushort8v*)(sB + (wn * 64 + tt * 16 + l16) * 32 + sw8));
        #pragma unroll
        for (int mt = 0; mt < 8; ++mt)
            #pragma unroll
            for (int nt = 0; nt < 4; ++nt)
                acc[mt][nt] = __builtin_amdgcn_mfma_f32_16x16x32_bf16(af[mt], bfr[nt], acc[mt][nt], 0, 0, 0);
        __asm volatile("s_barrier" ::: "memory");   // frag reads done before buffer reuse
        if (++bufc == 3) bufc = 0;
    }
    #undef STAGE

    float b4[4];
    #pragma unroll
    for (int nt = 0; nt < 4; ++nt) b4[nt] = bias[n0 + wn * 64 + nt * 16 + l16];

    if (EPI == 0 || EPI == 2) {
        // ---- bf16 output: bounce 256x128 to LDS, store packed uint4 ----
        unsigned short (*swB)[136] = (unsigned short (*)[136])smem;  // 256x136x2 = 69632B
        const int seg = n0 >> 8;                      // EPI0: 0=q 1=k 2=v (block never straddles)
        const float qs = (EPI == 0 && seg == 0) ? SCALE_ : 1.0f;
        #pragma unroll
        for (int mt = 0; mt < 8; ++mt)
            #pragma unroll
            for (int nt = 0; nt < 4; ++nt)
                #pragma unroll
                for (int r = 0; r < 4; ++r) {
                    float v = acc[mt][nt][r] + b4[nt];
                    if (EPI == 0) v *= qs; else v = gelu_t(v);
                    swB[wm * 128 + mt * 16 + quad * 4 + r][wn * 64 + nt * 16 + l16] = f2bf(v);
                }
        __syncthreads();
        if (EPI == 0) {
            unsigned short* dstp = seg == 0 ? outQ : (seg == 1 ? outK : outV);
            const int nbase = n0 & 255;
            for (int tt = tid; tt < 4096; tt += 256) {
                int row = tt >> 4, c8 = (tt & 15) * 8;
                int m = m0 + row, bw = m / NN, nw = m - bw * NN;
                int cc = nbase + c8;
                uint4 u = *(uint4*)&swB[row][c8];
                *(uint4*)&dstp[(((size_t)bw * NH_ + (cc >> 5)) * NN + nw) * HD_ + (cc & 31)] = u;
            }
        } else {
            for (int tt = tid; tt < 4096; tt += 256) {
                int row = tt >> 4, c8 = (tt & 15) * 8;
                uint4 u = *(uint4*)&swB[row][c8];
                *(uint4*)&outQ[(size_t)(m0 + row) * 1024 + n0 + c8] = u;
            }
        }
    } else {
        // ---- fp32 output: two 128-row passes through LDS, float4 RMW ----
        float (*swF)[132] = (float (*)[132])smem;     // 128x132x4 = 67584B
        #pragma unroll
        for (int p = 0; p < 2; ++p) {
            __syncthreads();
            if (wm == p) {
                #pragma unroll
                for (int mt = 0; mt < 8; ++mt)
                    #pragma unroll
                    for (int nt = 0; nt < 4; ++nt)
                        #pragma unroll
                        for (int r = 0; r < 4; ++r)
                            swF[mt * 16 + quad * 4 + r][wn * 64 + nt * 16 + l16] = acc[mt][nt][r] + b4[nt];
            }
            __syncthreads();
            for (int tt = tid; tt < 4096; tt += 256) {
                int rl = tt >> 5, c4 = (tt & 31) * 4;
                size_t adr;
                if (EPI == 1) {                       // window-reverse + unshift
                    int m = m0 + p * 128 + rl, bw = m / NN, nw = m - bw * NN;
                    int b = bw >> 6, wi = bw & 63;
                    int sh = (wi >> 3) * WS_ + nw / WS_;
                    int sw = (wi & 7) * WS_ + nw % WS_;
                    int ph = sh + SS_; if (ph >= HH)  ph -= HH;
                    int pw = sw + SS_; if (pw >= WWI) pw -= WWI;
                    adr = ((size_t)b * 3136 + ph * 56 + pw) * C_ + n0 + c4;
                } else {
                    adr = (size_t)(m0 + p * 128 + rl) * C_ + n0 + c4;
                }
                float4 u = *(float4*)&swF[rl][c4];
                const float4 rr = (EPI == 1) ? *(const float4*)&resid[adr]
                                             : *(const float4*)&outF[adr];
                u.x += rr.x; u.y += rr.y; u.z += rr.z; u.w += rr.w;
                *(float4*)&outF[adr] = u;
            }
        }
    }
}

// ---------------- MFMA attention: one block per (window, head) ----------------
__global__ __launch_bounds__(256) void attn_k(
    const unsigned short* __restrict__ qb, const unsigned short* __restrict__ kb,
    const unsigned short* __restrict__ vb, const unsigned short* __restrict__ cb,
    unsigned short* __restrict__ ob)
{
    __shared__ unsigned short qs[64][40];   // Q rows (pad 40: frag reads 2-way free)
    __shared__ unsigned short ks[64][40];   // K rows
    __shared__ unsigned short vt[32][72];   // V^T: [d][j], j padded to 64 (zeroed 49..63)
    __shared__ unsigned short sp[64][72];   // P bf16, A-layout rows
    __shared__ unsigned short cbs[2408];    // bias+mask slice
    const int tid = threadIdx.x;
    const int bw = blockIdx.x >> 3, head = blockIdx.x & 7;
    const size_t base = (size_t)blockIdx.x * (NN * HD_);   // (bw*8+head)*1568

    for (int t = tid; t < 588; t += 256) {
        int seg = t / 196, idx = t - seg * 196;
        int e = idx * 8;                          // 8 shorts = 16B
        const unsigned short* src = (seg == 0 ? qb : seg == 1 ? kb : vb) + base + e;
        uint4 u = *(const uint4*)src;
        if (seg == 0)      *(uint4*)&qs[e >> 5][e & 31] = u;
        else if (seg == 1) *(uint4*)&ks[e >> 5][e & 31] = u;
        else {
            int n = e >> 5, hd = e & 31;
            const unsigned short* pu = (const unsigned short*)&u;
            #pragma unroll
            for (int uu = 0; uu < 8; ++uu) vt[hd + uu][n] = pu[uu];
        }
    }
    {
        const unsigned short* cbase = cb + (size_t)(((bw & 63) * 8 + head)) * 2408;
        for (int t = tid; t < 301; t += 256)
            *(uint4*)&cbs[t * 8] = *(const uint4*)(cbase + t * 8);
        for (int t = tid; t < 480; t += 256) vt[t / 15][NN + t % 15] = 0;  // zero j=49..63
    }
    __syncthreads();

    const int wave = tid >> 6, lane = tid & 63, quad = lane >> 4, l16 = lane & 15;
    const f32x4 zz = {};

    bf16x8 afq = __builtin_bit_cast(bf16x8, *(const ushort8v*)&qs[wave * 16 + l16][quad * 8]);
    f32x4 s4[4];
    #pragma unroll
    for (int jt = 0; jt < 4; ++jt) {
        bf16x8 bk = __builtin_bit_cast(bf16x8, *(const ushort8v*)&ks[jt * 16 + l16][quad * 8]);
        s4[jt] = __builtin_amdgcn_mfma_f32_16x16x32_bf16(afq, bk, zz, 0, 0, 0);
    }

    #pragma unroll
    for (int r = 0; r < 4; ++r) {
        int i = wave * 16 + quad * 4 + r;
        float vals[4];
        #pragma unroll
        for (int jt = 0; jt < 4; ++jt) {
            int j = jt * 16 + l16;
            vals[jt] = (i < NN && j < NN) ? s4[jt][r] + bf2f(cbs[i * NN + j]) : -1e30f;
        }
        float mx = fmaxf(fmaxf(vals[0], vals[1]), fmaxf(vals[2], vals[3]));
        #pragma unroll
        for (int o = 1; o < 16; o <<= 1) mx = fmaxf(mx, __shfl_xor(mx, o, 64));
        float e[4], sum = 0.0f;
        #pragma unroll
        for (int jt = 0; jt < 4; ++jt) { e[jt] = __expf(vals[jt] - mx); sum += e[jt]; }
        #pragma unroll
        for (int o = 1; o < 16; o <<= 1) sum += __shfl_xor(sum, o, 64);
        float inv = 1.0f / sum;
        #pragma unroll
        for (int jt = 0; jt < 4; ++jt) sp[i][jt * 16 + l16] = f2bf(e[jt] * inv);
    }
    __syncthreads();

    bf16x8 ap[2];
    #pragma unroll
    for (int kt = 0; kt < 2; ++kt)
        ap[kt] = __builtin_bit_cast(bf16x8, *(const ushort8v*)&sp[wave * 16 + l16][kt * 32 + quad * 8]);
    f32x4 o4[2] = {};
    #pragma unroll
    for (int nt = 0; nt < 2; ++nt)
        #pragma unroll
        for (int kt = 0; kt < 2; ++kt) {
            bf16x8 bv = __builtin_bit_cast(bf16x8, *(const ushort8v*)&vt[nt * 16 + l16][kt * 32 + quad * 8]);
            o4[nt] = __builtin_amdgcn_mfma_f32_16x16x32_bf16(ap[kt], bv, o4[nt], 0, 0, 0);
        }
    #pragma unroll
    for (int nt = 0; nt < 2; ++nt)
        #pragma unroll
        for (int r = 0; r < 4; ++r) {
            int i = wave * 16 + quad * 4 + r;
            if (i < NN)
                ob[((size_t)bw * NN + i) * C_ + head * HD_ + nt * 16 + l16] = f2bf(o4[nt][r]);
        }
}

extern "C" void kernel_launch(void* const* d_in, const int* in_sizes, int n_in,
                              void* d_out, int out_size, void* d_ws, size_t ws_size,
                              hipStream_t stream)
{
    const float* x     = (const float*)d_in[0];
    const float* mask  = (const float*)d_in[1];
    const float* n1g   = (const float*)d_in[2];
    const float* n1b   = (const float*)d_in[3];
    const float* qkvw  = (const float*)d_in[4];
    const float* qkvb  = (const float*)d_in[5];
    const float* relb  = (const float*)d_in[6];
    const float* projw = (const float*)d_in[7];
    const float* projb = (const float*)d_in[8];
    const float* n2g   = (const float*)d_in[9];
    const float* n2b   = (const float*)d_in[10];
    const float* fc1w  = (const float*)d_in[11];
    const float* fc1b  = (const float*)d_in[12];
    const float* fc2w  = (const float*)d_in[13];
    const float* fc2b  = (const float*)d_in[14];
    float* out = (float*)d_out;

    unsigned short* wq = (unsigned short*)d_ws;   // all weights bf16, contiguous
    unsigned short* wp = wq + 196608;
    unsigned short* w1 = wq + 262144;
    unsigned short* w2 = wq + 524288;
    unsigned short* hw = wq + 786432;             // LN1-shift-partitioned (50176,256) bf16
    unsigned short* qb = hw + 12845056;           // (1024,8,49,32) bf16
    unsigned short* kb = qb + 12845056;
    unsigned short* vb = kb + 12845056;
    unsigned short* ob = vb + 12845056;           // attn out, windowed (50176,256) bf16
    unsigned short* h2 = ob + 12845056;           // LN2 out (50176,256) bf16
    unsigned short* a1 = h2 + 12845056;           // GELU(fc1) (50176,1024) bf16
    unsigned short* cbt = a1;                     // cb aliases a1 (attn_k finishes before FC1 writes a1)

    convw_k<<<3072, 256, 0, stream>>>(qkvw, projw, fc1w, fc2w, wq);
    cb_k<<<512, 256, 0, stream>>>(mask, relb, cbt);
    ln_k<<<12544, 256, 0, stream>>>(x, n1g, n1b, hw, 1);
    gemm_k<0, 6><<<196 * 6, 256, 0, stream>>>(hw, wq, 256, qkvb, nullptr, nullptr, qb, kb, vb);
    attn_k<<<8192, 256, 0, stream>>>(qb, kb, vb, cbt, ob);
    gemm_k<1, 2><<<196 * 2, 256, 0, stream>>>(ob, wp, 256, projb, x, out, nullptr, nullptr, nullptr);
    ln_k<<<12544, 256, 0, stream>>>(out, n2g, n2b, h2, 0);
    gemm_k<2, 8><<<196 * 8, 256, 0, stream>>>(h2, w1, 256, fc1b, nullptr, nullptr, a1, nullptr, nullptr);
    gemm_k<3, 2><<<196 * 2, 256, 0, stream>>>(a1, w2, 1024, fc2b, nullptr, out, nullptr, nullptr, nullptr);
}

// Round 5
// 372.883 us; speedup vs baseline: 1.8554x; 1.0764x over previous
//
#include <hip/hip_runtime.h>
#include <cmath>

#define B_    16
#define HH    56
#define WWI   56
#define C_    256
#define NH_   8
#define WS_   7
#define SS_   3
#define HD_   32
#define NTOK  50176          // B*56*56
#define NN    49             // window size squared
#define SCALE_ 0.17677669529663689f
#define EPS_  1e-5f

typedef __bf16  bf16x8  __attribute__((ext_vector_type(8)));
typedef float   f32x4   __attribute__((ext_vector_type(4)));
typedef unsigned short ushort8v __attribute__((ext_vector_type(8)));

__device__ __forceinline__ unsigned short f2bf(float f) {
    unsigned int u = __float_as_uint(f);
    unsigned int r = u + 0x7FFFu + ((u >> 16) & 1u);   // RNE
    return (unsigned short)(r >> 16);
}
__device__ __forceinline__ float bf2f(unsigned short h) {
    return __uint_as_float(((unsigned int)h) << 16);
}
// tanh-form GELU: |err| <= ~3e-3 vs exact erf form; hw v_exp_f32 + rcp
__device__ __forceinline__ float gelu_t(float x) {
    float t = 0.7978845608028654f * (x + 0.044715f * x * x * x);
    float e = __expf(2.0f * t);
    float th = 1.0f - 2.0f * __builtin_amdgcn_rcpf(e + 1.0f);
    return 0.5f * x * (1.0f + th);
}

// async global->LDS DMA, 16B per lane; deposits at wave-uniform lds base + lane*16
__device__ __forceinline__ void gload_lds16(const unsigned short* g, unsigned short* l) {
    __builtin_amdgcn_global_load_lds(
        (const __attribute__((address_space(1))) unsigned int*)g,
        (__attribute__((address_space(3))) unsigned int*)l, 16, 0, 0);
}

// ---------------- fused prep: weights fp32->bf16 + rel-bias/mask table -------
__global__ __launch_bounds__(256) void prep_k(
    const float* __restrict__ qkvw, const float* __restrict__ projw,
    const float* __restrict__ fc1w, const float* __restrict__ fc2w,
    unsigned short* __restrict__ dst,
    const float* __restrict__ mask, const float* __restrict__ relb,
    unsigned short* __restrict__ cb)
{
    if (blockIdx.x < 3072) {
        int i = blockIdx.x * 256 + threadIdx.x;          // < 786432
        float v;
        if      (i < 196608) v = qkvw[i];
        else if (i < 262144) v = projw[i - 196608];
        else if (i < 524288) v = fc1w[i - 262144];
        else                 v = fc2w[i - 524288];
        dst[i] = f2bf(v);
    } else {
        int s = blockIdx.x - 3072;          // 512 slices = 64 windows * 8 heads
        int wi = s >> 3, head = s & 7;
        for (int p = threadIdx.x; p < 2408; p += 256) {
            float v = 0.0f;
            if (p < 2401) {
                int i = p / NN, j = p - i * NN;
                int di = i / 7 - j / 7 + 6, dj = i % 7 - j % 7 + 6;
                v = relb[(di * 13 + dj) * NH_ + head] + mask[(size_t)wi * 2401 + p];
            }
            cb[(size_t)s * 2408 + p] = f2bf(v);
        }
    }
}

// ---------------- LayerNorm (+optional shift+window-partition) ----------------
__global__ __launch_bounds__(256) void ln_k(
    const float* __restrict__ x, const float* __restrict__ g,
    const float* __restrict__ bta, unsigned short* __restrict__ dst, int shifted)
{
    int wave = threadIdx.x >> 6, lane = threadIdx.x & 63;
    int tok = blockIdx.x * 4 + wave;                  // < 50176
    const float4 v = *(const float4*)(x + (size_t)tok * C_ + lane * 4);
    float s = v.x + v.y + v.z + v.w;
    float q = v.x*v.x + v.y*v.y + v.z*v.z + v.w*v.w;
    for (int o = 32; o > 0; o >>= 1) { s += __shfl_xor(s, o, 64); q += __shfl_xor(q, o, 64); }
    float mu  = s * (1.0f / C_);
    float var = q * (1.0f / C_) - mu * mu;
    float rs  = rsqrtf(var + EPS_);
    float4 gg = *(const float4*)(g   + lane * 4);
    float4 bb = *(const float4*)(bta + lane * 4);
    float y0 = (v.x - mu) * rs * gg.x + bb.x;
    float y1 = (v.y - mu) * rs * gg.y + bb.y;
    float y2 = (v.z - mu) * rs * gg.z + bb.z;
    float y3 = (v.w - mu) * rs * gg.w + bb.w;
    size_t di;
    if (shifted) {
        int b = tok / 3136, p = tok % 3136;
        int ph = p / 56, pw = p % 56;
        int sh = ph - SS_; if (sh < 0) sh += HH;
        int sw = pw - SS_; if (sw < 0) sw += WWI;
        int bw = b * 64 + (sh / WS_) * 8 + (sw / WS_);
        int n  = (sh % WS_) * WS_ + (sw % WS_);
        di = ((size_t)bw * NN + n) * C_ + lane * 4;
    } else {
        di = (size_t)tok * C_ + lane * 4;
    }
    unsigned int lo = (unsigned int)f2bf(y0) | ((unsigned int)f2bf(y1) << 16);
    unsigned int hi = (unsigned int)f2bf(y2) | ((unsigned int)f2bf(y3) << 16);
    uint2 u; u.x = lo; u.y = hi;
    *(uint2*)(dst + di) = u;
}

// ---------------- MFMA GEMM, 128x128 tile, BK=32, depth-2 DMA, 4 blk/CU ------
// R1/R2/R4 series shows dur is monotone in resident blocks/CU (1->91us,
// ~2->75us, 3->62.9us) at fixed staged bytes: concurrency-limited, each
// block-step idles ~80% (4700cy wall vs ~750cy critical path). Push 3->4
// blocks/CU: LDS 48->32KB (2 staging buffers, depth-2 counted vmcnt(4),
// same 2-barrier schedule) + __launch_bounds__(256,4) forcing unified
// VGPR <= 128 (est live ~114 = 64 acc + 32 frags + ~18 addr).
// T2 swizzle unchanged from R2 (conflicts measured 0): slot q of row r holds
// global chunk q ^ ((r>>1)&3); DMA keeps linear LDS dest with pre-permuted
// per-lane global source; frag reads undo via sw8.
template<int EPI, int NT>
__global__ __launch_bounds__(256, 4) void gemm_k(
    const unsigned short* __restrict__ A, const unsigned short* __restrict__ Bt,
    int K, const float* __restrict__ bias,
    const float* __restrict__ resid, float* __restrict__ outF,
    unsigned short* __restrict__ outQ, unsigned short* __restrict__ outK,
    unsigned short* __restrict__ outV)
{
    // smem: 2 x 16KB staging buffers; epilogue bounce overlays within 32KB
    __shared__ __align__(16) unsigned char smem[32768];
    const int tid = threadIdx.x;
    const int lin = blockIdx.x;
    const int xcd = lin & 7, t = lin >> 3;
    const int m0 = (xcd * 49 + t / NT) * 128;
    const int n0 = (t % NT) * 128;
    const int wave = tid >> 6, lane = tid & 63, quad = lane >> 4, l16 = lane & 15;
    const int wm = wave >> 1, wn = wave & 1;
    // staging row/col: row = tid>>2; source chunk = (tid&3) ^ ((row>>1)&3)
    const int r0 = tid >> 2;
    const int c0 = (((tid & 3) ^ ((tid >> 3) & 3)) * 8);

    const size_t gA0 = (size_t)(m0 + r0) * K + c0;
    const size_t gA1 = (size_t)(m0 + r0 + 64) * K + c0;
    const size_t gB0 = (size_t)(n0 + r0) * K + c0;
    const size_t gB1 = (size_t)(n0 + r0 + 64) * K + c0;
    const int woff = wave * 512;
    // read-side swizzle slot (loop-invariant; frag row base multiple of 16)
    const int sw8 = (quad ^ ((l16 >> 1) & 3)) * 8;

    f32x4 acc[4][4] = {};
    const int nk = K >> 5;

    #define STAGE(kt_, p_) { \
        unsigned short* sA_ = (unsigned short*)(smem + (p_) * 16384); \
        unsigned short* sB_ = sA_ + 4096; \
        const int kp_ = (kt_) << 5; \
        gload_lds16(A + gA0 + kp_, sA_ + woff); \
        gload_lds16(A + gA1 + kp_, sA_ + woff + 2048); \
        gload_lds16(Bt + gB0 + kp_, sB_ + woff); \
        gload_lds16(Bt + gB1 + kp_, sB_ + woff + 2048); }

    STAGE(0, 0);
    for (int kk = 0; kk < nk; ++kk) {
        const int p = kk & 1;
        if (kk + 1 < nk) {                 // prefetch tile kk+1 into other buf
            STAGE(kk + 1, p ^ 1);
            __asm volatile("s_waitcnt vmcnt(4)\n\ts_barrier" ::: "memory");
        } else {
            __asm volatile("s_waitcnt vmcnt(0)\n\ts_barrier" ::: "memory");
        }
        const unsigned short* sA = (const unsigned short*)(smem + p * 16384);
        const unsigned short* sB = sA + 4096;
        bf16x8 af[4], bfr[4];
        #pragma unroll
        for (int tt = 0; tt < 4; ++tt) {
            af[tt]  = __builtin_bit_cast(bf16x8, *(const ushort8v*)(sA + (wm * 64 + tt * 16 + l16) * 32 + sw8));
            bfr[tt] = __builtin_bit_cast(bf16x8, *(const ushort8v*)(sB + (wn * 64 + tt * 16 + l16) * 32 + sw8));
        }
        #pragma unroll
        for (int mt = 0; mt < 4; ++mt)
            #pragma unroll
            for (int nt = 0; nt < 4; ++nt)
                acc[mt][nt] = __builtin_amdgcn_mfma_f32_16x16x32_bf16(af[mt], bfr[nt], acc[mt][nt], 0, 0, 0);
        __asm volatile("s_barrier" ::: "memory");   // frag reads done before buffer reuse
    }
    #undef STAGE

    float b4[4];
    #pragma unroll
    for (int nt = 0; nt < 4; ++nt) b4[nt] = bias[n0 + wn * 64 + nt * 16 + l16];

    if (EPI == 0 || EPI == 2) {
        // ---- bf16 output: two 64-row passes through LDS, packed uint4 ----
        unsigned short (*swB)[136] = (unsigned short (*)[136])smem;  // 64x136x2 = 17408B
        const int seg = n0 >> 8;                      // EPI0: 0=q 1=k 2=v (block never straddles)
        const float qs = (EPI == 0 && seg == 0) ? SCALE_ : 1.0f;
        #pragma unroll
        for (int p = 0; p < 2; ++p) {
            __syncthreads();
            if (wm == p) {
                #pragma unroll
                for (int mt = 0; mt < 4; ++mt)
                    #pragma unroll
                    for (int nt = 0; nt < 4; ++nt)
                        #pragma unroll
                        for (int r = 0; r < 4; ++r) {
                            float v = acc[mt][nt][r] + b4[nt];
                            if (EPI == 0) v *= qs; else v = gelu_t(v);
                            swB[mt * 16 + quad * 4 + r][wn * 64 + nt * 16 + l16] = f2bf(v);
                        }
            }
            __syncthreads();
            if (EPI == 0) {
                unsigned short* dstp = seg == 0 ? outQ : (seg == 1 ? outK : outV);
                const int nbase = n0 & 255;
                for (int tt = tid; tt < 1024; tt += 256) {
                    int row = tt >> 4, c8 = (tt & 15) * 8;
                    int m = m0 + p * 64 + row, bw = m / NN, nw = m - bw * NN;
                    int cc = nbase + c8;
                    uint4 u = *(uint4*)&swB[row][c8];
                    *(uint4*)&dstp[(((size_t)bw * NH_ + (cc >> 5)) * NN + nw) * HD_ + (cc & 31)] = u;
                }
            } else {
                for (int tt = tid; tt < 1024; tt += 256) {
                    int row = tt >> 4, c8 = (tt & 15) * 8;
                    uint4 u = *(uint4*)&swB[row][c8];
                    *(uint4*)&outQ[(size_t)(m0 + p * 64 + row) * 1024 + n0 + c8] = u;
                }
            }
        }
    } else {
        // ---- fp32 output: four 32-row passes through LDS, float4 RMW ----
        float (*swF)[132] = (float (*)[132])smem;     // 32x132x4 = 16896B
        #pragma unroll
        for (int p = 0; p < 4; ++p) {
            __syncthreads();
            if (wm == (p >> 1)) {
                const int mtb = (p & 1) * 2;
                #pragma unroll
                for (int mt = 0; mt < 2; ++mt)
                    #pragma unroll
                    for (int nt = 0; nt < 4; ++nt)
                        #pragma unroll
                        for (int r = 0; r < 4; ++r)
                            swF[mt * 16 + quad * 4 + r][wn * 64 + nt * 16 + l16] =
                                acc[mtb + mt][nt][r] + b4[nt];
            }
            __syncthreads();
            for (int tt = tid; tt < 1024; tt += 256) {
                int rl = tt >> 5, c4 = (tt & 31) * 4;
                size_t adr;
                if (EPI == 1) {                       // window-reverse + unshift
                    int m = m0 + p * 32 + rl, bw = m / NN, nw = m - bw * NN;
                    int b = bw >> 6, wi = bw & 63;
                    int sh = (wi >> 3) * WS_ + nw / WS_;
                    int sw = (wi & 7) * WS_ + nw % WS_;
                    int ph = sh + SS_; if (ph >= HH)  ph -= HH;
                    int pw = sw + SS_; if (pw >= WWI) pw -= WWI;
                    adr = ((size_t)b * 3136 + ph * 56 + pw) * C_ + n0 + c4;
                } else {
                    adr = (size_t)(m0 + p * 32 + rl) * C_ + n0 + c4;
                }
                float4 u = *(float4*)&swF[rl][c4];
                const float4 rr = (EPI == 1) ? *(const float4*)&resid[adr]
                                             : *(const float4*)&outF[adr];
                u.x += rr.x; u.y += rr.y; u.z += rr.z; u.w += rr.w;
                *(float4*)&outF[adr] = u;
            }
        }
    }
}

// ---------------- MFMA attention: one block per (window, head) ----------------
__global__ __launch_bounds__(256) void attn_k(
    const unsigned short* __restrict__ qb, const unsigned short* __restrict__ kb,
    const unsigned short* __restrict__ vb, const unsigned short* __restrict__ cb,
    unsigned short* __restrict__ ob)
{
    __shared__ unsigned short qs[64][40];   // Q rows (pad 40: frag reads 2-way free)
    __shared__ unsigned short ks[64][40];   // K rows
    __shared__ unsigned short vt[32][72];   // V^T: [d][j], j padded to 64 (zeroed 49..63)
    __shared__ unsigned short sp[64][72];   // P bf16, A-layout rows
    __shared__ unsigned short cbs[2408];    // bias+mask slice
    const int tid = threadIdx.x;
    const int bw = blockIdx.x >> 3, head = blockIdx.x & 7;
    const size_t base = (size_t)blockIdx.x * (NN * HD_);   // (bw*8+head)*1568

    for (int t = tid; t < 588; t += 256) {
        int seg = t / 196, idx = t - seg * 196;
        int e = idx * 8;                          // 8 shorts = 16B
        const unsigned short* src = (seg == 0 ? qb : seg == 1 ? kb : vb) + base + e;
        uint4 u = *(const uint4*)src;
        if (seg == 0)      *(uint4*)&qs[e >> 5][e & 31] = u;
        else if (seg == 1) *(uint4*)&ks[e >> 5][e & 31] = u;
        else {
            int n = e >> 5, hd = e & 31;
            const unsigned short* pu = (const unsigned short*)&u;
            #pragma unroll
            for (int uu = 0; uu < 8; ++uu) vt[hd + uu][n] = pu[uu];
        }
    }
    {
        const unsigned short* cbase = cb + (size_t)(((bw & 63) * 8 + head)) * 2408;
        for (int t = tid; t < 301; t += 256)
            *(uint4*)&cbs[t * 8] = *(const uint4*)(cbase + t * 8);
        for (int t = tid; t < 480; t += 256) vt[t / 15][NN + t % 15] = 0;  // zero j=49..63
    }
    __syncthreads();

    const int wave = tid >> 6, lane = tid & 63, quad = lane >> 4, l16 = lane & 15;
    const f32x4 zz = {};

    bf16x8 afq = __builtin_bit_cast(bf16x8, *(const ushort8v*)&qs[wave * 16 + l16][quad * 8]);
    f32x4 s4[4];
    #pragma unroll
    for (int jt = 0; jt < 4; ++jt) {
        bf16x8 bk = __builtin_bit_cast(bf16x8, *(const ushort8v*)&ks[jt * 16 + l16][quad * 8]);
        s4[jt] = __builtin_amdgcn_mfma_f32_16x16x32_bf16(afq, bk, zz, 0, 0, 0);
    }

    #pragma unroll
    for (int r = 0; r < 4; ++r) {
        int i = wave * 16 + quad * 4 + r;
        float vals[4];
        #pragma unroll
        for (int jt = 0; jt < 4; ++jt) {
            int j = jt * 16 + l16;
            vals[jt] = (i < NN && j < NN) ? s4[jt][r] + bf2f(cbs[i * NN + j]) : -1e30f;
        }
        float mx = fmaxf(fmaxf(vals[0], vals[1]), fmaxf(vals[2], vals[3]));
        #pragma unroll
        for (int o = 1; o < 16; o <<= 1) mx = fmaxf(mx, __shfl_xor(mx, o, 64));
        float e[4], sum = 0.0f;
        #pragma unroll
        for (int jt = 0; jt < 4; ++jt) { e[jt] = __expf(vals[jt] - mx); sum += e[jt]; }
        #pragma unroll
        for (int o = 1; o < 16; o <<= 1) sum += __shfl_xor(sum, o, 64);
        float inv = 1.0f / sum;
        #pragma unroll
        for (int jt = 0; jt < 4; ++jt) sp[i][jt * 16 + l16] = f2bf(e[jt] * inv);
    }
    __syncthreads();

    bf16x8 ap[2];
    #pragma unroll
    for (int kt = 0; kt < 2; ++kt)
        ap[kt] = __builtin_bit_cast(bf16x8, *(const ushort8v*)&sp[wave * 16 + l16][kt * 32 + quad * 8]);
    f32x4 o4[2] = {};
    #pragma unroll
    for (int nt = 0; nt < 2; ++nt)
        #pragma unroll
        for (int kt = 0; kt < 2; ++kt) {
            bf16x8 bv = __builtin_bit_cast(bf16x8, *(const ushort8v*)&vt[nt * 16 + l16][kt * 32 + quad * 8]);
            o4[nt] = __builtin_amdgcn_mfma_f32_16x16x32_bf16(ap[kt], bv, o4[nt], 0, 0, 0);
        }
    #pragma unroll
    for (int nt = 0; nt < 2; ++nt)
        #pragma unroll
        for (int r = 0; r < 4; ++r) {
            int i = wave * 16 + quad * 4 + r;
            if (i < NN)
                ob[((size_t)bw * NN + i) * C_ + head * HD_ + nt * 16 + l16] = f2bf(o4[nt][r]);
        }
}

extern "C" void kernel_launch(void* const* d_in, const int* in_sizes, int n_in,
                              void* d_out, int out_size, void* d_ws, size_t ws_size,
                              hipStream_t stream)
{
    const float* x     = (const float*)d_in[0];
    const float* mask  = (const float*)d_in[1];
    const float* n1g   = (const float*)d_in[2];
    const float* n1b   = (const float*)d_in[3];
    const float* qkvw  = (const float*)d_in[4];
    const float* qkvb  = (const float*)d_in[5];
    const float* relb  = (const float*)d_in[6];
    const float* projw = (const float*)d_in[7];
    const float* projb = (const float*)d_in[8];
    const float* n2g   = (const float*)d_in[9];
    const float* n2b   = (const float*)d_in[10];
    const float* fc1w  = (const float*)d_in[11];
    const float* fc1b  = (const float*)d_in[12];
    const float* fc2w  = (const float*)d_in[13];
    const float* fc2b  = (const float*)d_in[14];
    float* out = (float*)d_out;

    unsigned short* wq = (unsigned short*)d_ws;   // all weights bf16, contiguous
    unsigned short* wp = wq + 196608;
    unsigned short* w1 = wq + 262144;
    unsigned short* w2 = wq + 524288;
    unsigned short* hw = wq + 786432;             // LN1-shift-partitioned (50176,256) bf16
    unsigned short* qb = hw + 12845056;           // (1024,8,49,32) bf16
    unsigned short* kb = qb + 12845056;
    unsigned short* vb = kb + 12845056;
    unsigned short* ob = vb + 12845056;           // attn out, windowed (50176,256) bf16
    unsigned short* h2 = ob + 12845056;           // LN2 out (50176,256) bf16
    unsigned short* a1 = h2 + 12845056;           // GELU(fc1) (50176,1024) bf16
    unsigned short* cbt = a1;                     // cb aliases a1 (attn_k finishes before FC1 writes a1)

    prep_k<<<3584, 256, 0, stream>>>(qkvw, projw, fc1w, fc2w, wq, mask, relb, cbt);
    ln_k<<<12544, 256, 0, stream>>>(x, n1g, n1b, hw, 1);
    gemm_k<0, 6><<<392 * 6, 256, 0, stream>>>(hw, wq, 256, qkvb, nullptr, nullptr, qb, kb, vb);
    attn_k<<<8192, 256, 0, stream>>>(qb, kb, vb, cbt, ob);
    gemm_k<1, 2><<<392 * 2, 256, 0, stream>>>(ob, wp, 256, projb, x, out, nullptr, nullptr, nullptr);
    ln_k<<<12544, 256, 0, stream>>>(out, n2g, n2b, h2, 0);
    gemm_k<2, 8><<<392 * 8, 256, 0, stream>>>(h2, w1, 256, fc1b, nullptr, nullptr, a1, nullptr, nullptr);
    gemm_k<3, 2><<<392 * 2, 256, 0, stream>>>(a1, w2, 1024, fc2b, nullptr, out, nullptr, nullptr, nullptr);
}